// Round 6
// baseline (684.561 us; speedup 1.0000x reference)
//
#include <hip/hip_runtime.h>
#include <hip/hip_bf16.h>

#define S_ 64
#define P_ 32
#define N_ 2048
#define H_ 64
#define E_ 64
#define D1_ 512
#define D2_ 1024
#define EPS_ 1e-5f

typedef unsigned short u16;
using bf16x8 = __attribute__((ext_vector_type(8))) __bf16;
using floatx4 = __attribute__((ext_vector_type(4))) float;

__device__ inline u16 f2bf(float x) {
    unsigned u = __float_as_uint(x);
    unsigned r = (u + 0x7fffu + ((u >> 16) & 1u)) >> 16;
    return (u16)r;
}
__device__ inline unsigned bf2pack(float lo, float hi) {
    return (unsigned)f2bf(lo) | ((unsigned)f2bf(hi) << 16);
}

// ---- fused prep ----
// blocks 0..255: scene part. block = (scene s, d-quarter dq); threads = 4 jg x 128 dl.
//   Each thread computes w[8],u[8] for its 8 j's and 1 channel; BN1 stats via LDS reduce.
// blocks 256..383: W2 transpose+bf16.
__global__ __launch_bounds__(512)
void k_prep(const float* __restrict__ pos, const float* __restrict__ h,
            const float* __restrict__ We, const float* __restrict__ W1,
            const float* __restrict__ g1, const float* __restrict__ be1,
            const float* __restrict__ W2,
            float* __restrict__ A, float* __restrict__ Bv, u16* __restrict__ w2t) {
    __shared__ float smem[4160];
    const int bid = blockIdx.x;
    const int tid = threadIdx.x;
    if (bid < 256) {
        const int s = bid >> 2, dq = bid & 3;
        const int jg = tid >> 7, dl = tid & 127;
        const int d = (dq << 7) + dl;
        float* hs = smem;           // 2048: h[j][e]
        float* ps = smem + 2048;    // 64: pos
        float* red = smem + 2112;   // 2048: 4 stats x 512 threads
        for (int i = tid; i < P_ * H_; i += 512) hs[i] = h[(size_t)s * P_ * H_ + i];
        if (tid < 64) ps[tid] = pos[s * 64 + tid];
        __syncthreads();
        // wq = We^T W1a column d
        float wq0 = 0.f, wq1 = 0.f;
        for (int e = 0; e < E_; ++e) {
            const float wv = W1[e * D1_ + d];
            wq0 += We[e] * wv;
            wq1 += We[E_ + e] * wv;
        }
        // w[jj] = h[j] @ W1b[:,d]
        float w[8], u[8];
#pragma unroll
        for (int jj = 0; jj < 8; ++jj) w[jj] = 0.f;
        const float4* h4 = (const float4*)hs;
        for (int e4 = 0; e4 < 16; ++e4) {
            const float c0 = W1[(E_ + e4 * 4 + 0) * D1_ + d];
            const float c1 = W1[(E_ + e4 * 4 + 1) * D1_ + d];
            const float c2 = W1[(E_ + e4 * 4 + 2) * D1_ + d];
            const float c3 = W1[(E_ + e4 * 4 + 3) * D1_ + d];
#pragma unroll
            for (int jj = 0; jj < 8; ++jj) {
                const float4 hv = h4[((jg << 3) + jj) * 16 + e4];
                w[jj] += hv.x * c0 + hv.y * c1 + hv.z * c2 + hv.w * c3;
            }
        }
        float sw = 0.f, sww = 0.f, su = 0.f, suu = 0.f;
#pragma unroll
        for (int jj = 0; jj < 8; ++jj) {
            const int j = (jg << 3) + jj;
            u[jj] = ps[2 * j] * wq0 + ps[2 * j + 1] * wq1;
            w[jj] += u[jj];
            sw += w[jj]; sww += w[jj] * w[jj];
            su += u[jj]; suu += u[jj] * u[jj];
        }
        red[(jg << 7) + dl] = sw;
        red[512 + (jg << 7) + dl] = sww;
        red[1024 + (jg << 7) + dl] = su;
        red[1536 + (jg << 7) + dl] = suu;
        __syncthreads();
        float tw = 0.f, tww = 0.f, tu = 0.f, tuu = 0.f;
#pragma unroll
        for (int g = 0; g < 4; ++g) {
            tw += red[(g << 7) + dl];
            tww += red[512 + (g << 7) + dl];
            tu += red[1024 + (g << 7) + dl];
            tuu += red[1536 + (g << 7) + dl];
        }
        const float mw = tw * (1.f / P_), mu = tu * (1.f / P_);
        const float var = (tww * (1.f / P_) - mw * mw) + (tuu * (1.f / P_) - mu * mu);
        const float sc = rsqrtf(var + EPS_) * g1[d];
        const float bb = be1[d];
#pragma unroll
        for (int jj = 0; jj < 8; ++jj) {
            const int j = (jg << 3) + jj;
            A[(size_t)(s * P_ + j) * D1_ + d] = (w[jj] - mw) * sc + bb;
            Bv[(size_t)(s * P_ + j) * D1_ + d] = (u[jj] - mu) * sc;
        }
    } else {
        const int b2 = bid - 256;       // 0..127
        const int bi = b2 & 15;         // n tile (64)
        const int bj = b2 >> 4;         // k tile (64)
        const int tx = tid & 63, ty = tid >> 6;  // 64 x 8
        float (*tile)[65] = (float (*)[65])smem;
#pragma unroll
        for (int i = 0; i < 64; i += 8)
            tile[ty + i][tx] = W2[(size_t)(bj * 64 + ty + i) * D2_ + bi * 64 + tx];
        __syncthreads();
#pragma unroll
        for (int i = 0; i < 64; i += 8)
            w2t[(size_t)(bi * 64 + ty + i) * D1_ + bj * 64 + tx] = f2bf(tile[tx][ty + i]);
    }
}

// ---- fused GEMM: block = 128 rows (4 peds x 32 j) x 512 cols, 8 waves.
// Per K-slice(64): As (16 KB, per-lane relu-diff, proven XOR layout) +
// Ws (64 KB via global_load_lds); each wave 64 MFMA (tm4 x tn8). 16 barriers.
__global__ __launch_bounds__(512, 4)
void k_gemm(const float* __restrict__ A, const float* __restrict__ B,
            const u16* __restrict__ w2t,
            float* __restrict__ maxv, float* __restrict__ minv,
            float* __restrict__ psum, float* __restrict__ psumsq) {
    __shared__ u16 As[128 * 64];   // 16 KB
    __shared__ u16 Ws[512 * 64];   // 64 KB
    const int cs = blockIdx.x;     // col half 0..1
    const int mt = blockIdx.y;     // M tile 0..511
    const int s = mt >> 3, rb = mt & 7;
    const int pedb = rb << 2;
    const int N0 = cs << 9;
    const int tid = threadIdx.x;
    const int wave = tid >> 6, lane = tid & 63;
    const int wm = wave >> 2, wn = wave & 3;   // 2 x 4 wave grid
    const int quad = lane >> 4, l16 = lane & 15;
    const int lrow = lane >> 3, lchk = lane & 7;
    const int gchk = lchk ^ lrow;

    floatx4 acc[4][8] = {};

    for (int it = 0; it < 8; ++it) {
        const int k0 = it << 6;
        // ---- stage Ws: 512 rows x 64 k via global_load_lds ----
#pragma unroll
        for (int t = 0; t < 8; ++t) {
            const int rbase = (wave << 6) + (t << 3);
            const u16* gb = w2t + (size_t)(N0 + rbase + lrow) * D1_ + (k0 + (gchk << 3));
            __builtin_amdgcn_global_load_lds(
                (const __attribute__((address_space(1))) void*)gb,
                (__attribute__((address_space(3))) void*)(Ws + (rbase << 6)), 16, 0, 0);
        }
        // ---- stage As: 128 rows (4 peds x 32 j) x 64 k, per-lane relu-diff ----
#pragma unroll
        for (int t = 0; t < 2; ++t) {
            const int slot = tid + (t << 9);
            const int r = slot >> 3, c = slot & 7;
            const int j = r & 31, p = r >> 5;
            const float* Aj = A + ((size_t)(s * 32 + j) << 9) + (c << 3) + k0;
            const float* Bp = B + ((size_t)(s * 32 + pedb + p) << 9) + (c << 3) + k0;
            const float4 alo = *(const float4*)Aj;
            const float4 ahi = *(const float4*)(Aj + 4);
            const float4 blo = *(const float4*)Bp;
            const float4 bhi = *(const float4*)(Bp + 4);
            uint4 o;
            o.x = bf2pack(fmaxf(alo.x - blo.x, 0.f), fmaxf(alo.y - blo.y, 0.f));
            o.y = bf2pack(fmaxf(alo.z - blo.z, 0.f), fmaxf(alo.w - blo.w, 0.f));
            o.z = bf2pack(fmaxf(ahi.x - bhi.x, 0.f), fmaxf(ahi.y - bhi.y, 0.f));
            o.w = bf2pack(fmaxf(ahi.z - bhi.z, 0.f), fmaxf(ahi.w - bhi.w, 0.f));
            *(uint4*)(As + (r << 6) + ((c ^ (r & 7)) << 3)) = o;
        }
        __syncthreads();
        // ---- compute: 2 kk x (af4 x wf8) = 64 MFMA per wave ----
#pragma unroll
        for (int kk = 0; kk < 2; ++kk) {
            const int ck = (kk << 2) + quad;
            const int po = (ck ^ (l16 & 7)) << 3;
            bf16x8 af[4], wf[8];
#pragma unroll
            for (int tm = 0; tm < 4; ++tm) {
                const int row = (wm << 6) + (tm << 4) + l16;
                af[tm] = *(const bf16x8*)(As + (row << 6) + po);
            }
#pragma unroll
            for (int tn = 0; tn < 8; ++tn) {
                const int row = (wn << 7) + (tn << 4) + l16;
                wf[tn] = *(const bf16x8*)(Ws + (row << 6) + po);
            }
#pragma unroll
            for (int tm = 0; tm < 4; ++tm)
#pragma unroll
                for (int tn = 0; tn < 8; ++tn)
                    acc[tm][tn] = __builtin_amdgcn_mfma_f32_16x16x32_bf16(
                        af[tm], wf[tn], acc[tm][tn], 0, 0, 0);
        }
        __syncthreads();
    }

    // ---- epilogue: j-max/min per ped + BN2 partial sums ----
    // acc row_local = wm*64 + tm*16 + quad*4 + r; ped = pedb + wm*2 + (tm>>1)
#pragma unroll
    for (int tn = 0; tn < 8; ++tn) {
        const int col = N0 + (wn << 7) + (tn << 4) + l16;
        float wsum = 0.f, wsq = 0.f;
#pragma unroll
        for (int gp = 0; gp < 2; ++gp) {
            float vmax = -3.4e38f, vmin = 3.4e38f, vs = 0.f, vq = 0.f;
#pragma unroll
            for (int tm = gp * 2; tm < gp * 2 + 2; ++tm)
#pragma unroll
                for (int r = 0; r < 4; ++r) {
                    const float v = acc[tm][tn][r];
                    vmax = fmaxf(vmax, v);
                    vmin = fminf(vmin, v);
                    vs += v;
                    vq += v * v;
                }
#pragma unroll
            for (int off = 16; off < 64; off <<= 1) {
                vmax = fmaxf(vmax, __shfl_xor(vmax, off));
                vmin = fminf(vmin, __shfl_xor(vmin, off));
                vs += __shfl_xor(vs, off);
                vq += __shfl_xor(vq, off);
            }
            if (quad == 0) {
                const int kg = s * 32 + pedb + (wm << 1) + gp;
                maxv[(size_t)kg * D2_ + col] = vmax;
                minv[(size_t)kg * D2_ + col] = vmin;
            }
            wsum += vs;
            wsq += vq;
        }
        if (quad == 0) {
            const int slot = (s << 4) + (rb << 1) + wm;  // 16 slots per scene
            psum[(size_t)slot * D2_ + col] = wsum;
            psumsq[(size_t)slot * D2_ + col] = wsq;
        }
    }
}

// ---- BN2 + relu on the j-maxed values ----
__global__ void k_final(const float* __restrict__ maxv, const float* __restrict__ minv,
                        const float* __restrict__ psum, const float* __restrict__ psumsq,
                        const float* __restrict__ g2, const float* __restrict__ be2,
                        float* __restrict__ out) {
    const int c = blockIdx.x * 256 + threadIdx.x;  // 0..1023
    const int s = blockIdx.y;
    float sm = 0.f, sq = 0.f;
#pragma unroll
    for (int t = 0; t < 16; ++t) {
        sm += psum[(size_t)(s * 16 + t) * D2_ + c];
        sq += psumsq[(size_t)(s * 16 + t) * D2_ + c];
    }
    const float mu = sm * (1.f / 1024.f);
    const float var = sq * (1.f / 1024.f) - mu * mu;
    const float inv = rsqrtf(var + EPS_);
    const float scale = g2[c] * inv;
    const float bb = be2[c];
    const float* src = (scale >= 0.f) ? maxv : minv;  // BN monotone direction
    for (int k = 0; k < 32; ++k) {
        const float v = src[(size_t)(s * 32 + k) * D2_ + c];
        out[(size_t)(s * 32 + k) * D2_ + c] = fmaxf((v - mu) * scale + bb, 0.f);
    }
}

extern "C" void kernel_launch(void* const* d_in, const int* in_sizes, int n_in,
                              void* d_out, int out_size, void* d_ws, size_t ws_size,
                              hipStream_t stream) {
    const float* h_states = (const float*)d_in[0];
    const float* end_pos = (const float*)d_in[2];
    const float* W_embed = (const float*)d_in[4];
    const float* W1 = (const float*)d_in[6];
    const float* g1 = (const float*)d_in[8];
    const float* be1 = (const float*)d_in[9];
    const float* W2 = (const float*)d_in[10];
    const float* g2 = (const float*)d_in[12];
    const float* be2 = (const float*)d_in[13];
    float* out = (float*)d_out;

    float* Abuf = (float*)d_ws;                // 1,048,576 f
    float* Bbuf = Abuf + 1048576;              // 1,048,576 f
    float* maxv = Bbuf + 1048576;              // 2,097,152 f
    float* minv = maxv + 2097152;              // 2,097,152 f
    float* psum = minv + 2097152;              // 1,048,576 f
    float* psumsq = psum + 1048576;            // 1,048,576 f
    u16* w2t = (u16*)(psumsq + 1048576);       // 524,288 u16

    k_prep<<<dim3(384), dim3(512), 0, stream>>>(end_pos, h_states, W_embed, W1,
                                                g1, be1, W2, Abuf, Bbuf, w2t);
    k_gemm<<<dim3(2, 512), dim3(512), 0, stream>>>(Abuf, Bbuf, w2t, maxv, minv, psum, psumsq);
    k_final<<<dim3(4, 64), dim3(256), 0, stream>>>(maxv, minv, psum, psumsq, g2, be2, out);
}

// Round 7
// 262.725 us; speedup vs baseline: 2.6056x; 2.6056x over previous
//
#include <hip/hip_runtime.h>
#include <hip/hip_bf16.h>

#define S_ 64
#define P_ 32
#define N_ 2048
#define H_ 64
#define E_ 64
#define D1_ 512
#define D2_ 1024
#define EPS_ 1e-5f

typedef unsigned short u16;
using bf16x8 = __attribute__((ext_vector_type(8))) __bf16;
using floatx4 = __attribute__((ext_vector_type(4))) float;

__device__ inline u16 f2bf(float x) {
    unsigned u = __float_as_uint(x);
    unsigned r = (u + 0x7fffu + ((u >> 16) & 1u)) >> 16;
    return (u16)r;
}
__device__ inline unsigned bf2pack(float lo, float hi) {
    return (unsigned)f2bf(lo) | ((unsigned)f2bf(hi) << 16);
}

// ---- fused prep ----
// blocks 0..255: scene part. block = (scene s, d-quarter dq); threads = 4 jg x 128 dl.
// blocks 256..383: W2 transpose+bf16.
__global__ __launch_bounds__(512)
void k_prep(const float* __restrict__ pos, const float* __restrict__ h,
            const float* __restrict__ We, const float* __restrict__ W1,
            const float* __restrict__ g1, const float* __restrict__ be1,
            const float* __restrict__ W2,
            float* __restrict__ A, float* __restrict__ Bv, u16* __restrict__ w2t) {
    __shared__ float smem[4160];
    const int bid = blockIdx.x;
    const int tid = threadIdx.x;
    if (bid < 256) {
        const int s = bid >> 2, dq = bid & 3;
        const int jg = tid >> 7, dl = tid & 127;
        const int d = (dq << 7) + dl;
        float* hs = smem;           // 2048: h[j][e]
        float* ps = smem + 2048;    // 64: pos
        float* red = smem + 2112;   // 2048: 4 stats x 512 threads
        for (int i = tid; i < P_ * H_; i += 512) hs[i] = h[(size_t)s * P_ * H_ + i];
        if (tid < 64) ps[tid] = pos[s * 64 + tid];
        __syncthreads();
        float wq0 = 0.f, wq1 = 0.f;
        for (int e = 0; e < E_; ++e) {
            const float wv = W1[e * D1_ + d];
            wq0 += We[e] * wv;
            wq1 += We[E_ + e] * wv;
        }
        float w[8], u[8];
#pragma unroll
        for (int jj = 0; jj < 8; ++jj) w[jj] = 0.f;
        const float4* h4 = (const float4*)hs;
        for (int e4 = 0; e4 < 16; ++e4) {
            const float c0 = W1[(E_ + e4 * 4 + 0) * D1_ + d];
            const float c1 = W1[(E_ + e4 * 4 + 1) * D1_ + d];
            const float c2 = W1[(E_ + e4 * 4 + 2) * D1_ + d];
            const float c3 = W1[(E_ + e4 * 4 + 3) * D1_ + d];
#pragma unroll
            for (int jj = 0; jj < 8; ++jj) {
                const float4 hv = h4[((jg << 3) + jj) * 16 + e4];
                w[jj] += hv.x * c0 + hv.y * c1 + hv.z * c2 + hv.w * c3;
            }
        }
        float sw = 0.f, sww = 0.f, su = 0.f, suu = 0.f;
#pragma unroll
        for (int jj = 0; jj < 8; ++jj) {
            const int j = (jg << 3) + jj;
            u[jj] = ps[2 * j] * wq0 + ps[2 * j + 1] * wq1;
            w[jj] += u[jj];
            sw += w[jj]; sww += w[jj] * w[jj];
            su += u[jj]; suu += u[jj] * u[jj];
        }
        red[(jg << 7) + dl] = sw;
        red[512 + (jg << 7) + dl] = sww;
        red[1024 + (jg << 7) + dl] = su;
        red[1536 + (jg << 7) + dl] = suu;
        __syncthreads();
        float tw = 0.f, tww = 0.f, tu = 0.f, tuu = 0.f;
#pragma unroll
        for (int g = 0; g < 4; ++g) {
            tw += red[(g << 7) + dl];
            tww += red[512 + (g << 7) + dl];
            tu += red[1024 + (g << 7) + dl];
            tuu += red[1536 + (g << 7) + dl];
        }
        const float mw = tw * (1.f / P_), mu = tu * (1.f / P_);
        const float var = (tww * (1.f / P_) - mw * mw) + (tuu * (1.f / P_) - mu * mu);
        const float sc = rsqrtf(var + EPS_) * g1[d];
        const float bb = be1[d];
#pragma unroll
        for (int jj = 0; jj < 8; ++jj) {
            const int j = (jg << 3) + jj;
            A[(size_t)(s * P_ + j) * D1_ + d] = (w[jj] - mw) * sc + bb;
            Bv[(size_t)(s * P_ + j) * D1_ + d] = (u[jj] - mu) * sc;
        }
    } else {
        const int b2 = bid - 256;       // 0..127
        const int bi = b2 & 15;         // n tile (64)
        const int bj = b2 >> 4;         // k tile (64)
        const int tx = tid & 63, ty = tid >> 6;  // 64 x 8
        float (*tile)[65] = (float (*)[65])smem;
#pragma unroll
        for (int i = 0; i < 64; i += 8)
            tile[ty + i][tx] = W2[(size_t)(bj * 64 + ty + i) * D2_ + bi * 64 + tx];
        __syncthreads();
#pragma unroll
        for (int i = 0; i < 64; i += 8)
            w2t[(size_t)(bi * 64 + ty + i) * D1_ + bj * 64 + tx] = f2bf(tile[tx][ty + i]);
    }
}

// ---- fused GEMM: block = 128 rows (4 peds x 32 j) x 256 cols, 4 waves (R5 tile).
// As (x1 K-slice) built in LDS per-lane, DOUBLE-buffered -> 1 barrier per slice.
// W fragments loaded DIRECTLY from L2-resident w2t (no Ws LDS): the MFMA
// B-operand layout (row = col, 8 consecutive k per lane) is exactly a 16 B
// global load at w2t[row*512 + k0 + ck*8]. 8 row pointers precomputed,
// k-offsets are immediates.
__global__ __launch_bounds__(256, 2)
void k_gemm(const float* __restrict__ A, const float* __restrict__ B,
            const u16* __restrict__ w2t,
            float* __restrict__ maxv, float* __restrict__ minv,
            float* __restrict__ psum, float* __restrict__ psumsq) {
    __shared__ u16 As[2][128 * 64];   // 2 x 16 KB
    const int cs = blockIdx.x;     // col split 0..3
    const int mt = blockIdx.y;     // M tile 0..511
    const int s = mt >> 3, rb = mt & 7;
    const int pedb = rb << 2;
    const int N0 = cs << 8;
    const int tid = threadIdx.x;
    const int wave = tid >> 6, lane = tid & 63;
    const int wm = wave >> 1, wn = wave & 1;
    const int quad = lane >> 4, l16 = lane & 15;

    // As staging mapping (proven R5 scheme, conflicts == 0)
    const int sj = tid >> 3, sc8 = tid & 7;
    const float* Aj = A + ((size_t)(s * 32 + sj) << 9) + (sc8 << 3);
    const float* Bp = B + ((size_t)(s * 32 + pedb) << 9) + (sc8 << 3);
    const int swz = (sc8 ^ (sj & 7)) << 3;

    // per-lane W row pointers (col = row of w2t), + quad k-offset folded in
    const u16* wp[8];
#pragma unroll
    for (int tn = 0; tn < 8; ++tn)
        wp[tn] = w2t + (size_t)(N0 + (wn << 7) + (tn << 4) + l16) * D1_ + (quad << 3);

    floatx4 acc[4][8] = {};

#define STAGE_AS(IT, BUF)                                                        \
    {                                                                            \
        const int k0s = (IT) << 6;                                               \
        _Pragma("unroll")                                                        \
        for (int p = 0; p < 4; ++p) {                                            \
            const int r = (p << 5) + sj;                                         \
            const float4 alo = *(const float4*)(Aj + k0s);                       \
            const float4 ahi = *(const float4*)(Aj + k0s + 4);                   \
            const float4 blo = *(const float4*)(Bp + ((size_t)p << 9) + k0s);    \
            const float4 bhi = *(const float4*)(Bp + ((size_t)p << 9) + k0s + 4);\
            uint4 o;                                                             \
            o.x = bf2pack(fmaxf(alo.x - blo.x, 0.f), fmaxf(alo.y - blo.y, 0.f)); \
            o.y = bf2pack(fmaxf(alo.z - blo.z, 0.f), fmaxf(alo.w - blo.w, 0.f)); \
            o.z = bf2pack(fmaxf(ahi.x - bhi.x, 0.f), fmaxf(ahi.y - bhi.y, 0.f)); \
            o.w = bf2pack(fmaxf(ahi.z - bhi.z, 0.f), fmaxf(ahi.w - bhi.w, 0.f)); \
            *(uint4*)(As[BUF] + (r << 6) + swz) = o;                             \
        }                                                                        \
    }

    STAGE_AS(0, 0);
    __syncthreads();

    for (int it = 0; it < 8; ++it) {
        const int buf = it & 1;
        const int k0 = it << 6;
        // direct W fragment loads for both kk of this slice (independent of As)
        bf16x8 wf[2][8];
#pragma unroll
        for (int kk = 0; kk < 2; ++kk)
#pragma unroll
            for (int tn = 0; tn < 8; ++tn)
                wf[kk][tn] = *(const bf16x8*)(wp[tn] + k0 + (kk << 5));
        // stage next As slice into the other buffer (no barrier needed here:
        // last reader of As[buf^1] synced at the previous barrier)
        if (it < 7) STAGE_AS(it + 1, buf ^ 1);
#pragma unroll
        for (int kk = 0; kk < 2; ++kk) {
            const int ck = (kk << 2) + quad;
            const int po = (ck ^ (l16 & 7)) << 3;
            bf16x8 af[4];
#pragma unroll
            for (int tm = 0; tm < 4; ++tm) {
                const int row = (wm << 6) + (tm << 4) + l16;
                af[tm] = *(const bf16x8*)(As[buf] + (row << 6) + po);
            }
#pragma unroll
            for (int tm = 0; tm < 4; ++tm)
#pragma unroll
                for (int tn = 0; tn < 8; ++tn)
                    acc[tm][tn] = __builtin_amdgcn_mfma_f32_16x16x32_bf16(
                        af[tm], wf[kk][tn], acc[tm][tn], 0, 0, 0);
        }
        __syncthreads();
    }
#undef STAGE_AS

    // ---- epilogue: j-max/min per ped + BN2 partial sums (unchanged from R5) ----
#pragma unroll
    for (int tn = 0; tn < 8; ++tn) {
        const int col = N0 + (wn << 7) + (tn << 4) + l16;
        float wsum = 0.f, wsq = 0.f;
#pragma unroll
        for (int gp = 0; gp < 2; ++gp) {
            float vmax = -3.4e38f, vmin = 3.4e38f, vs = 0.f, vq = 0.f;
#pragma unroll
            for (int tm = gp * 2; tm < gp * 2 + 2; ++tm)
#pragma unroll
                for (int r = 0; r < 4; ++r) {
                    const float v = acc[tm][tn][r];
                    vmax = fmaxf(vmax, v);
                    vmin = fminf(vmin, v);
                    vs += v;
                    vq += v * v;
                }
#pragma unroll
            for (int off = 16; off < 64; off <<= 1) {
                vmax = fmaxf(vmax, __shfl_xor(vmax, off));
                vmin = fminf(vmin, __shfl_xor(vmin, off));
                vs += __shfl_xor(vs, off);
                vq += __shfl_xor(vq, off);
            }
            if (quad == 0) {
                const int kg = s * 32 + pedb + (wm << 1) + gp;
                maxv[(size_t)kg * D2_ + col] = vmax;
                minv[(size_t)kg * D2_ + col] = vmin;
            }
            wsum += vs;
            wsq += vq;
        }
        if (quad == 0) {
            const int slot = (s << 4) + (rb << 1) + wm;  // 16 slots per scene
            psum[(size_t)slot * D2_ + col] = wsum;
            psumsq[(size_t)slot * D2_ + col] = wsq;
        }
    }
}

// ---- BN2 + relu on the j-maxed values ----
__global__ void k_final(const float* __restrict__ maxv, const float* __restrict__ minv,
                        const float* __restrict__ psum, const float* __restrict__ psumsq,
                        const float* __restrict__ g2, const float* __restrict__ be2,
                        float* __restrict__ out) {
    const int c = blockIdx.x * 256 + threadIdx.x;  // 0..1023
    const int s = blockIdx.y;
    float sm = 0.f, sq = 0.f;
#pragma unroll
    for (int t = 0; t < 16; ++t) {
        sm += psum[(size_t)(s * 16 + t) * D2_ + c];
        sq += psumsq[(size_t)(s * 16 + t) * D2_ + c];
    }
    const float mu = sm * (1.f / 1024.f);
    const float var = sq * (1.f / 1024.f) - mu * mu;
    const float inv = rsqrtf(var + EPS_);
    const float scale = g2[c] * inv;
    const float bb = be2[c];
    const float* src = (scale >= 0.f) ? maxv : minv;  // BN monotone direction
    for (int k = 0; k < 32; ++k) {
        const float v = src[(size_t)(s * 32 + k) * D2_ + c];
        out[(size_t)(s * 32 + k) * D2_ + c] = fmaxf((v - mu) * scale + bb, 0.f);
    }
}

extern "C" void kernel_launch(void* const* d_in, const int* in_sizes, int n_in,
                              void* d_out, int out_size, void* d_ws, size_t ws_size,
                              hipStream_t stream) {
    const float* h_states = (const float*)d_in[0];
    const float* end_pos = (const float*)d_in[2];
    const float* W_embed = (const float*)d_in[4];
    const float* W1 = (const float*)d_in[6];
    const float* g1 = (const float*)d_in[8];
    const float* be1 = (const float*)d_in[9];
    const float* W2 = (const float*)d_in[10];
    const float* g2 = (const float*)d_in[12];
    const float* be2 = (const float*)d_in[13];
    float* out = (float*)d_out;

    float* Abuf = (float*)d_ws;                // 1,048,576 f
    float* Bbuf = Abuf + 1048576;              // 1,048,576 f
    float* maxv = Bbuf + 1048576;              // 2,097,152 f
    float* minv = maxv + 2097152;              // 2,097,152 f
    float* psum = minv + 2097152;              // 1,048,576 f
    float* psumsq = psum + 1048576;            // 1,048,576 f
    u16* w2t = (u16*)(psumsq + 1048576);       // 524,288 u16

    k_prep<<<dim3(384), dim3(512), 0, stream>>>(end_pos, h_states, W_embed, W1,
                                                g1, be1, W2, Abuf, Bbuf, w2t);
    k_gemm<<<dim3(4, 512), dim3(256), 0, stream>>>(Abuf, Bbuf, w2t, maxv, minv, psum, psumsq);
    k_final<<<dim3(4, 64), dim3(256), 0, stream>>>(maxv, minv, psum, psumsq, g2, be2, out);
}